// Round 11
// baseline (5388.944 us; speedup 1.0000x reference)
//
#include <hip/hip_runtime.h>
#include <math.h>

#define NOT_FIREDf 9999.0f
typedef float f32x2 __attribute__((ext_vector_type(2)));

// packed f32x2 add (bit-exact element-wise IEEE add, 1 inst for 2 adds)
#define PKADD(ACC, W) asm("v_pk_add_f32 %0, %0, %1" : "+v"(ACC) : "v"(W))

// Zero-padded conv2 weights in d_ws:
// w2p[((ci*5 + dy)*19 + rx)*64 + co] = (rx-7 in [0,5)) ? w2[(co*12+ci)*25 + dy*5 + (rx-7)] : 0
__global__ void w2_pad_kernel(const float* __restrict__ w2, float* __restrict__ w2p) {
    int idx = blockIdx.x * 256 + threadIdx.x;
    if (idx >= 72960) return;
    int co = idx & 63;
    int r = idx >> 6;            // ci*95 + dy*19 + rx
    int rx = r % 19;
    int q = r / 19;
    int dy = q % 5;
    int ci = q / 5;
    int dx = rx - 7;
    w2p[idx] = ((unsigned)dx < 5u) ? w2[(co * 12 + ci) * 25 + dy * 5 + dx] : 0.0f;
}

// phase-1: one input event vs this thread's single owned pixel
#define P1EVENT(PK) do {                                                     \
    const int dy_ = (int)((PK) >> 8) - y0v;                                  \
    const int dx_ = (int)((PK) & 255u) - x0v;                                \
    if (((unsigned)dy_ < 5u) & ((unsigned)dx_ < 5u)) {                       \
        const f32x2* wp_ = (const f32x2*)&w1s[(dy_ * 5 + dx_) * 12];         \
        f32x2 a0_ = wp_[0], a1_ = wp_[1], a2_ = wp_[2];                      \
        f32x2 a3_ = wp_[3], a4_ = wp_[4], a5_ = wp_[5];                      \
        PKADD(v1r[0], a0_); PKADD(v1r[1], a1_); PKADD(v1r[2], a2_);          \
        PKADD(v1r[3], a3_); PKADD(v1r[4], a4_); PKADD(v1r[5], a5_);          \
    } } while (0)

// phase-2: one pooled-l1 event vs this wave's single v2 row (row_s)
#define P2_ONE(PA) do {                                                      \
    const int dyy_ = (((PA) >> 4) & 15) - row_s;                             \
    if ((unsigned)dyy_ < 5u) {                                               \
        const int ci_ = (PA) >> 8;                                           \
        const int px_ = (PA) & 15;                                           \
        const float* q_ = w2p + ((ci_ * 5 + dyy_) * 19 + px_ + 7) * 64 + lane; \
        f32x2 la_[4];                                                        \
        _Pragma("unroll")                                                    \
        for (int i = 0; i < 4; ++i) {                                        \
            la_[i].x = q_[-((2 * i) * 64)];                                  \
            la_[i].y = q_[-((2 * i + 1) * 64)];                              \
        }                                                                    \
        _Pragma("unroll")                                                    \
        for (int i = 0; i < 4; ++i) PKADD(v2r2[i], la_[i]);                  \
    } } while (0)

template <int USE_T>
__global__ void __launch_bounds__(576, 4)
snn_px_kernel(const float* __restrict__ img,
              const float* __restrict__ w1g,
              const float* __restrict__ b1g,
              const float* __restrict__ b2g,
              const float* __restrict__ w2raw,
              const float* __restrict__ w2p,
              const float* __restrict__ fcw,
              const float* __restrict__ b3g,
              float* __restrict__ out) {
    const int bimg = blockIdx.x;
    const int tid  = threadIdx.x;            // 0..575
    const int lane = tid & 63;
    const int wv   = tid >> 6;               // 0..8 (9 waves)
    const int row_s = __builtin_amdgcn_readfirstlane(wv);   // v2 row for waves 0-7

    __shared__ __align__(16) float w1s[300];   // transposed: [k=ky*5+kx][c]
    __shared__ __align__(8)  float b1s[12];
    __shared__ float th_lds[80];
    __shared__ unsigned char  stin[784];
    __shared__ unsigned short evlist[784];     // t-sorted schedule, packed (py<<8|px)
    __shared__ unsigned short off[81];
    __shared__ unsigned int   hist[80];
    __shared__ __align__(8) unsigned short ev1b[2][1728];  // pooled-l1 events, dbuf
    __shared__ int            cnt1[80];        // per-step counters, never reset
    __shared__ unsigned int   pm1[54];
    __shared__ unsigned int   pm2[32];
    __shared__ unsigned int   e2list[1024];    // persistent: (t<<16) | nhwc_flat_idx
    __shared__ int            e2_cnt;

    // ---- init (stride 576) ----
    for (int i = tid; i < 300; i += 576) {
        int k = i / 12, c = i - k * 12;
        w1s[i] = w1g[c * 25 + k];
    }
    if (tid < 12) b1s[tid] = b1g[tid];
    if (tid < 80) {
        float xa = (0.0f - (float)tid) / 20.0f;
        th_lds[tid] = (float)exp((double)xa);            // correctly-rounded f32 exp
        hist[tid] = 0u;
        cnt1[tid] = 0;
    }
    if (tid < 54) pm1[tid] = 0u;
    if (tid < 32) pm2[tid] = 0u;
    if (tid == 0) e2_cnt = 0;
    for (int i = tid; i < 784; i += 576) {
        float p = img[bimg * 784 + i];
        p = fmaxf(p, 1e-5f);
        float lg = (float)log((double)p);                // correctly-rounded f32 log
        float s = ceilf(fmaxf(-17.452274f * lg, 0.0f));
        stin[i] = (unsigned char)(int)fminf(s, 255.0f);
    }
    __syncthreads();
    for (int i = tid; i < 784; i += 576) {
        int t = stin[i];
        if (t < 80) atomicAdd(&hist[t], 1u);
    }
    __syncthreads();
    if (tid == 0) {
        unsigned int acc = 0;
        for (int t = 0; t < 80; ++t) { off[t] = (unsigned short)acc; acc += hist[t]; }
        off[80] = (unsigned short)acc;
    }
    __syncthreads();
    if (tid < 80) {                            // deterministic pixel-order fill per t-bin
        int k = off[tid];
        for (int i = 0; i < 784; ++i)
            if ((int)stin[i] == tid) {
                int py = i / 28;
                evlist[k++] = (unsigned short)((py << 8) | (i - py * 28));
            }
    }
    __syncthreads();

    // ---- register state (small!) ----
    // thread owns ONE conv1 pixel (y0v,x0v); wave wv (<8) owns v2 row wv with ch=lane
    const int y0v = tid / 24, x0v = tid - y0v * 24;
    const int pyp = y0v >> 1, pxp = x0v >> 1;
    f32x2 v1r[6];                              // 12 ch of the owned pixel
#pragma unroll
    for (int j = 0; j < 6; ++j) v1r[j] = (f32x2){0.0f, 0.0f};
    f32x2 v2r2[4];                             // cols (2i,2i+1) of row row_s
#pragma unroll
    for (int j = 0; j < 4; ++j) v2r2[j] = (f32x2){0.0f, 0.0f};
    const float b2v = b2g[lane];
    const f32x2 b2p = (f32x2){b2v, b2v};

    // ---- time loop: ONE barrier per step ----
    for (int t = 0; t < 80; ++t) {
        const float th = th_lds[t];

        // phase 1: input events -> owned v1 pixel (unroll-4 prefetch)
        {
            const int e0 = off[t], e1t = off[t + 1];
            int e = e0;
            for (; e + 4 <= e1t; e += 4) {
                const unsigned a0 = evlist[e];
                const unsigned a1 = evlist[e + 1];
                const unsigned a2 = evlist[e + 2];
                const unsigned a3 = evlist[e + 3];
                P1EVENT(a0); P1EVENT(a1); P1EVENT(a2); P1EVENT(a3);
            }
            for (; e < e1t; ++e) { const unsigned a = evlist[e]; P1EVENT(a); }
        }
        // layer1 check: stepwise bias (from LDS) + max-screen + rare exact pass
        {
            const f32x2* bp = (const f32x2*)b1s;
            f32x2 c0 = bp[0], c1 = bp[1], c2 = bp[2];
            f32x2 c3 = bp[3], c4 = bp[4], c5 = bp[5];
            PKADD(v1r[0], c0); PKADD(v1r[1], c1); PKADD(v1r[2], c2);
            PKADD(v1r[3], c3); PKADD(v1r[4], c4); PKADD(v1r[5], c5);
            float m = fmaxf(fmaxf(fmaxf(v1r[0].x, v1r[0].y), fmaxf(v1r[1].x, v1r[1].y)),
                            fmaxf(fmaxf(v1r[2].x, v1r[2].y), fmaxf(v1r[3].x, v1r[3].y)));
            m = fmaxf(m, fmaxf(fmaxf(v1r[4].x, v1r[4].y), fmaxf(v1r[5].x, v1r[5].y)));
            if (m >= th) {
#pragma unroll
                for (int jj = 0; jj < 6; ++jj) {
#pragma unroll
                    for (int el = 0; el < 2; ++el) {
                        const float v = el ? v1r[jj].y : v1r[jj].x;
                        if (v >= th) {
                            if (el) v1r[jj].y = -__builtin_inff();
                            else    v1r[jj].x = -__builtin_inff();
                            const int c = jj * 2 + el;
                            const int p = c * 144 + pyp * 12 + pxp;
                            const unsigned bit = 1u << (p & 31);
                            const unsigned old = atomicOr(&pm1[p >> 5], bit);
                            if (!(old & bit)) {
                                const int pos = atomicAdd(&cnt1[t], 1);
                                ev1b[t & 1][pos] =
                                    (unsigned short)((c << 8) | (pyp << 4) | pxp);
                            }
                        }
                    }
                }
            }
        }
        __syncthreads();                       // B1: ev1b[t&1]/cnt1[t] complete

        // phase 2 + layer2 check: waves 0-7 only (wave 8 owns no v2 row)
        if (row_s < 8) {
            const int ne1 = cnt1[t];
            const unsigned short* evp = ev1b[t & 1];
            if (USE_T) {
                int e = 0;
                for (; e + 4 <= ne1; e += 4) {
                    const unsigned long long pk4 = *(const unsigned long long*)&evp[e];
                    const unsigned lo = (unsigned)__builtin_amdgcn_readfirstlane((int)(unsigned)pk4);
                    const unsigned hi = (unsigned)__builtin_amdgcn_readfirstlane((int)(unsigned)(pk4 >> 32));
                    const int p0 = (int)(lo & 0xFFFFu), p1 = (int)(lo >> 16);
                    const int p2 = (int)(hi & 0xFFFFu), p3 = (int)(hi >> 16);
                    P2_ONE(p0); P2_ONE(p1); P2_ONE(p2); P2_ONE(p3);
                }
                for (; e < ne1; ++e) {
                    const int p0 = __builtin_amdgcn_readfirstlane((int)evp[e]);
                    P2_ONE(p0);
                }
            } else {
                for (int e = 0; e < ne1; ++e) {
                    const int pk = __builtin_amdgcn_readfirstlane((int)evp[e]);
                    const int dy = ((pk >> 4) & 15) - row_s;
                    if ((unsigned)dy >= 5u) continue;
                    const int ci = pk >> 8;
                    const int px = pk & 15;
                    const float* r = w2raw + (lane * 12 + ci) * 25 + dy * 5;
#pragma unroll
                    for (int i = 0; i < 4; ++i) {
                        const int dxa = px - 2 * i;
                        const int dxb = dxa - 1;
                        const int dxac = dxa < 0 ? 0 : (dxa > 4 ? 4 : dxa);
                        const int dxbc = dxb < 0 ? 0 : (dxb > 4 ? 4 : dxb);
                        v2r2[i].x = fmaf(r[dxac], ((unsigned)dxa < 5u) ? 1.0f : 0.0f, v2r2[i].x);
                        v2r2[i].y = fmaf(r[dxbc], ((unsigned)dxb < 5u) ? 1.0f : 0.0f, v2r2[i].y);
                    }
                }
            }
            // layer2: stepwise bias + max-screen + rare exact pass
            PKADD(v2r2[0], b2p); PKADD(v2r2[1], b2p);
            PKADD(v2r2[2], b2p); PKADD(v2r2[3], b2p);
            float m2 = fmaxf(fmaxf(fmaxf(v2r2[0].x, v2r2[0].y), fmaxf(v2r2[1].x, v2r2[1].y)),
                             fmaxf(fmaxf(v2r2[2].x, v2r2[2].y), fmaxf(v2r2[3].x, v2r2[3].y)));
            if (m2 >= th) {
#pragma unroll
                for (int i = 0; i < 4; ++i) {
#pragma unroll
                    for (int el = 0; el < 2; ++el) {
                        const float v = el ? v2r2[i].y : v2r2[i].x;
                        if (v >= th) {
                            if (el) v2r2[i].y = -__builtin_inff();
                            else    v2r2[i].x = -__builtin_inff();
                            // ox = 2i+el -> pw = i; oy = row_s -> ph = row_s>>1
                            const int p2 = ((row_s >> 1) * 4 + i) * 64 + lane;  // NHWC flat
                            const unsigned bit = 1u << (p2 & 31);
                            const unsigned old = atomicOr(&pm2[p2 >> 5], bit);
                            if (!(old & bit)) {
                                const int pos = atomicAdd(&e2_cnt, 1);
                                e2list[pos] = ((unsigned)t << 16) | (unsigned)p2;
                            }
                        }
                    }
                }
            }
        }
        // no second barrier: next step's phase 1 touches only ev1b[(t+1)&1]/cnt1[t+1]
    }
    __syncthreads();                           // e2list complete

    // ---- output layer: replay t-sorted layer2 event log (no feedback) ----
    if (tid < 10) {
        const int n2 = e2_cnt;
        const float b3v = b3g[tid];
        float v = 0.0f;
        float ot = NOT_FIREDf;
        int ptr = 0;
        for (int t = 0; t < 80; ++t) {
            float acc = 0.0f;
            while (ptr < n2 && (int)(e2list[ptr] >> 16) == t) {
                acc += fcw[(e2list[ptr] & 0xFFFFu) * 10 + tid];
                ++ptr;
            }
            v += acc + b3v;
            if (ot == NOT_FIREDf && v >= th_lds[t]) ot = (float)t;
        }
        out[bimg * 10 + tid] = ot;
    }
}

extern "C" void kernel_launch(void* const* d_in, const int* in_sizes, int n_in,
                              void* d_out, int out_size, void* d_ws, size_t ws_size,
                              hipStream_t stream) {
    const float* img = (const float*)d_in[0];
    const float* w1  = (const float*)d_in[1];
    const float* b1  = (const float*)d_in[2];
    const float* w2  = (const float*)d_in[3];
    const float* b2  = (const float*)d_in[4];
    const float* fcw = (const float*)d_in[5];
    const float* b3  = (const float*)d_in[6];
    float* out = (float*)d_out;

    const int B = in_sizes[0] / (28 * 28);

    float* w2p = (float*)d_ws;
    const int use_t = (ws_size >= 72960u * sizeof(float)) ? 1 : 0;
    if (use_t) {
        hipLaunchKernelGGL(w2_pad_kernel, dim3(285), dim3(256), 0, stream, w2, w2p);
        hipLaunchKernelGGL(snn_px_kernel<1>, dim3(B), dim3(576), 0, stream,
                           img, w1, b1, b2, w2, w2p, fcw, b3, out);
    } else {
        hipLaunchKernelGGL(snn_px_kernel<0>, dim3(B), dim3(576), 0, stream,
                           img, w1, b1, b2, w2, w2p, fcw, b3, out);
    }
}

// Round 12
// 3791.402 us; speedup vs baseline: 1.4214x; 1.4214x over previous
//
#include <hip/hip_runtime.h>
#include <math.h>

#define NOT_FIREDf 9999.0f
typedef float f32x2 __attribute__((ext_vector_type(2)));

// packed f32x2 add (bit-exact element-wise IEEE add, 1 inst for 2 adds)
#define PKADD(ACC, W) asm("v_pk_add_f32 %0, %0, %1" : "+v"(ACC) : "v"(W))

// Zero-padded conv2 weights in d_ws:
// w2p[((ci*5 + dy)*19 + rx)*64 + co] = (rx-7 in [0,5)) ? w2[(co*12+ci)*25 + dy*5 + (rx-7)] : 0
// plus a 19*64 zero row at w2p + 72960.
__global__ void w2_pad_kernel(const float* __restrict__ w2, float* __restrict__ w2p) {
    int idx = blockIdx.x * 256 + threadIdx.x;
    if (idx >= 74176) return;
    if (idx >= 72960) { w2p[idx] = 0.0f; return; }
    int co = idx & 63;
    int r = idx >> 6;            // ci*95 + dy*19 + rx
    int rx = r % 19;
    int q = r / 19;
    int dy = q % 5;
    int ci = q / 5;
    int dx = rx - 7;
    w2p[idx] = ((unsigned)dx < 5u) ? w2[(co * 12 + ci) * 25 + dy * 5 + dx] : 0.0f;
}

// v1 gather: 6 pk-adds of one w1 row (12 ch) into reg pairs
#define GATHER_V1(S, Y, X) do {                                              \
    const int dy_ = py - (Y), dx_ = px - (X);                                \
    if (((unsigned)dy_ < 5u) & ((unsigned)dx_ < 5u)) {                       \
        const f32x2* wp_ = (const f32x2*)&w1s[(dy_ * 5 + dx_) * 12];         \
        PKADD(v1r[S][0], wp_[0]); PKADD(v1r[S][1], wp_[1]);                  \
        PKADD(v1r[S][2], wp_[2]); PKADD(v1r[S][3], wp_[3]);                  \
        PKADD(v1r[S][4], wp_[4]); PKADD(v1r[S][5], wp_[5]);                  \
    } } while (0)

#define P1EVENT(PK) do {                                                     \
    const int py = (int)((PK) >> 8);                                         \
    const int px = (int)((PK) & 255u);                                       \
    GATHER_V1(0, y0, x0);                                                    \
    GATHER_V1(1, y1, x1);                                                    \
    if (has2) GATHER_V1(2, y2, x2);                                          \
  } while (0)

// stepwise bias pk-add + max-screen; exact per-channel pass only on crossing
#define CHECK_V1G(S, Y, X) do {                                              \
    PKADD(v1r[S][0], b1p[0]); PKADD(v1r[S][1], b1p[1]);                      \
    PKADD(v1r[S][2], b1p[2]); PKADD(v1r[S][3], b1p[3]);                      \
    PKADD(v1r[S][4], b1p[4]); PKADD(v1r[S][5], b1p[5]);                      \
    float m_ = fmaxf(fmaxf(fmaxf(v1r[S][0].x, v1r[S][0].y),                  \
                           fmaxf(v1r[S][1].x, v1r[S][1].y)),                 \
                     fmaxf(fmaxf(v1r[S][2].x, v1r[S][2].y),                  \
                           fmaxf(v1r[S][3].x, v1r[S][3].y)));                \
    m_ = fmaxf(m_, fmaxf(fmaxf(v1r[S][4].x, v1r[S][4].y),                    \
                         fmaxf(v1r[S][5].x, v1r[S][5].y)));                  \
    if (m_ >= th) {                                                          \
        _Pragma("unroll")                                                    \
        for (int jj = 0; jj < 6; ++jj) {                                     \
            _Pragma("unroll")                                                \
            for (int el = 0; el < 2; ++el) {                                 \
                const float v_ = el ? v1r[S][jj].y : v1r[S][jj].x;           \
                if (v_ >= th) {                                              \
                    if (el) v1r[S][jj].y = -__builtin_inff();                \
                    else    v1r[S][jj].x = -__builtin_inff();                \
                    const int c_ = jj * 2 + el;                              \
                    const int pyp_ = (Y) >> 1, pxp_ = (X) >> 1;              \
                    const int p_ = c_ * 144 + pyp_ * 12 + pxp_;              \
                    const unsigned bit_ = 1u << (p_ & 31);                   \
                    const unsigned old_ = atomicOr(&pm1[p_ >> 5], bit_);     \
                    if (!(old_ & bit_)) {                                    \
                        const int pos_ = atomicAdd(&cnt1[t], 1);             \
                        ev1b[t & 1][pos_] =                                  \
                            (unsigned short)((c_ << 8) | (pyp_ << 4) | pxp_);\
                    }                                                        \
                }                                                            \
            }                                                                \
        }                                                                    \
    } } while (0)

// one phase-2 event: 16 zero-padded loads -> 8 pk-adds (register-lean)
#define P2_ONE(PA) do {                                                      \
    const int dA_ = (((PA) >> 4) & 15) - oyb_s;                              \
    if ((unsigned)dA_ < 6u) {                                                \
        const int ci_ = (PA) >> 8;                                           \
        const int px_ = (PA) & 15;                                           \
        const float* r0_ = (dA_ <= 4) ? (w2p + (ci_ * 5 + dA_) * 1216) : zrow; \
        const float* r1_ = (dA_ >= 1) ? (w2p + (ci_ * 5 + dA_ - 1) * 1216) : zrow; \
        const float* q0_ = r0_ + (px_ + 7) * 64 + lane;                      \
        const float* q1_ = r1_ + (px_ + 7) * 64 + lane;                      \
        f32x2 la_[8];                                                        \
        _Pragma("unroll")                                                    \
        for (int j = 0; j < 8; ++j) { la_[j].x = q0_[-(j * 64)]; la_[j].y = q1_[-(j * 64)]; } \
        _Pragma("unroll")                                                    \
        for (int j = 0; j < 8; ++j) PKADD(v2r2[j], la_[j]);                  \
    } } while (0)

template <int USE_T>
__global__ void __launch_bounds__(256, 3)
snn_sim_kernel(const float* __restrict__ img,
               const float* __restrict__ w1g,
               const float* __restrict__ b1g,
               const float* __restrict__ b2g,
               const float* __restrict__ w2raw,
               const float* __restrict__ w2p,
               const float* __restrict__ fcw,
               const float* __restrict__ b3g,
               float* __restrict__ out) {
    const int bimg = blockIdx.x;
    const int tid  = threadIdx.x;
    const int lane = tid & 63;
    const int wv   = tid >> 6;   // 4 waves
    const int oyb_s = __builtin_amdgcn_readfirstlane(wv) * 2;   // wave-uniform SGPR

    __shared__ __align__(16) float w1s[300];   // transposed: [k=ky*5+kx][c]
    __shared__ float b1s[12];
    __shared__ float th_lds[80];
    __shared__ unsigned char  stin[784];
    __shared__ unsigned short evlist[784];     // t-sorted schedule, packed (py<<8|px)
    __shared__ unsigned short off[81];
    __shared__ unsigned int   hist[80];
    __shared__ __align__(8) unsigned short ev1b[2][1728];  // pooled-l1 events, dbuf
    __shared__ int            cnt1[80];        // per-step counters, never reset
    __shared__ unsigned int   pm1[54];
    __shared__ unsigned int   pm2[32];
    __shared__ unsigned int   e2list[1024];    // persistent: (t<<16) | nhwc_flat_idx
    __shared__ int            e2_cnt;

    // ---- init ----
    for (int i = tid; i < 300; i += 256) {
        int k = i / 12, c = i - k * 12;
        w1s[i] = w1g[c * 25 + k];
    }
    if (tid < 12) b1s[tid] = b1g[tid];
    if (tid < 80) {
        float xa = (0.0f - (float)tid) / 20.0f;
        th_lds[tid] = (float)exp((double)xa);            // correctly-rounded f32 exp
        hist[tid] = 0u;
        cnt1[tid] = 0;
    }
    if (tid < 54) pm1[tid] = 0u;
    if (tid < 32) pm2[tid] = 0u;
    if (tid == 0) e2_cnt = 0;
    for (int i = tid; i < 784; i += 256) {
        float p = img[bimg * 784 + i];
        p = fmaxf(p, 1e-5f);
        float lg = (float)log((double)p);                // correctly-rounded f32 log
        float s = ceilf(fmaxf(-17.452274f * lg, 0.0f));
        stin[i] = (unsigned char)(int)fminf(s, 255.0f);
    }
    __syncthreads();
    for (int i = tid; i < 784; i += 256) {
        int t = stin[i];
        if (t < 80) atomicAdd(&hist[t], 1u);
    }
    __syncthreads();
    if (tid == 0) {
        unsigned int acc = 0;
        for (int t = 0; t < 80; ++t) { off[t] = (unsigned short)acc; acc += hist[t]; }
        off[80] = (unsigned short)acc;
    }
    __syncthreads();
    if (tid < 80) {                            // deterministic pixel-order fill per t-bin
        int k = off[tid];
        for (int i = 0; i < 784; ++i)
            if ((int)stin[i] == tid) {
                int py = i / 28;
                evlist[k++] = (unsigned short)((py << 8) | (i - py * 28));
            }
    }
    __syncthreads();

    // ---- register state ----
    f32x2 v1r[3][6];
#pragma unroll
    for (int s = 0; s < 3; ++s)
#pragma unroll
        for (int j = 0; j < 6; ++j) v1r[s][j] = (f32x2){0.0f, 0.0f};
    f32x2 v2r2[8];                             // .x = row oyb, .y = row oyb+1, col j, co=lane
#pragma unroll
    for (int j = 0; j < 8; ++j) v2r2[j] = (f32x2){0.0f, 0.0f};

    f32x2 b1p[6];
#pragma unroll
    for (int j = 0; j < 6; ++j) b1p[j] = (f32x2){b1s[j * 2], b1s[j * 2 + 1]};
    const float b2v = b2g[lane];
    const f32x2 b2p = (f32x2){b2v, b2v};
    const float* zrow = w2p + 72960;

    const int y0 = tid / 24,  x0 = tid - y0 * 24;
    const int p1i = tid + 256;
    const int y1 = p1i / 24,  x1 = p1i - y1 * 24;
    const int has2 = (tid < 64);
    const int p2i = tid + 512;
    const int y2 = p2i / 24,  x2 = p2i - y2 * 24;

    // ---- time loop: ONE barrier per step ----
    for (int t = 0; t < 80; ++t) {
        const float th = th_lds[t];

        // phase 1: gather input events into v1 reg pairs (unroll-4 prefetch)
        {
            const int e0 = off[t], e1t = off[t + 1];
            int e = e0;
            for (; e + 4 <= e1t; e += 4) {
                const unsigned a0 = evlist[e];
                const unsigned a1 = evlist[e + 1];
                const unsigned a2 = evlist[e + 2];
                const unsigned a3 = evlist[e + 3];
                P1EVENT(a0); P1EVENT(a1); P1EVENT(a2); P1EVENT(a3);
            }
            for (; e < e1t; ++e) { const unsigned a = evlist[e]; P1EVENT(a); }
        }
        CHECK_V1G(0, y0, x0);
        CHECK_V1G(1, y1, x1);
        if (has2) CHECK_V1G(2, y2, x2);
        __syncthreads();                       // B1: ev1b[t&1]/cnt1[t] complete

        // phase 2: pooled-l1 events -> v2 (4 events per ds_read_b64, sequential P2)
        {
            const int ne1 = cnt1[t];
            const unsigned short* evp = ev1b[t & 1];
            if (USE_T) {
                int e = 0;
                for (; e + 4 <= ne1; e += 4) {
                    const unsigned long long pk4 = *(const unsigned long long*)&evp[e];
                    const unsigned lo = (unsigned)__builtin_amdgcn_readfirstlane((int)(unsigned)pk4);
                    const unsigned hi = (unsigned)__builtin_amdgcn_readfirstlane((int)(unsigned)(pk4 >> 32));
                    const int p0 = (int)(lo & 0xFFFFu), p1 = (int)(lo >> 16);
                    const int p2 = (int)(hi & 0xFFFFu), p3 = (int)(hi >> 16);
                    P2_ONE(p0); P2_ONE(p1); P2_ONE(p2); P2_ONE(p3);
                }
                for (; e < ne1; ++e) {
                    const int p0 = __builtin_amdgcn_readfirstlane((int)evp[e]);
                    P2_ONE(p0);
                }
            } else {
                for (int e = 0; e < ne1; ++e) {
                    const int pk = __builtin_amdgcn_readfirstlane((int)evp[e]);
                    const int dy0 = ((pk >> 4) & 15) - oyb_s;
                    if ((unsigned)dy0 >= 6u) continue;
                    const int ci = pk >> 8;
                    const int px = pk & 15;
                    const int dy1 = dy0 - 1;
                    const unsigned colm = ((0x1Fu << px) >> 4) & 0xFFu;
                    const unsigned m0 = ((unsigned)dy0 < 5u) ? colm : 0u;
                    const unsigned m1 = ((unsigned)dy1 < 5u) ? colm : 0u;
                    const int dy0c = dy0 < 0 ? 0 : (dy0 > 4 ? 4 : dy0);
                    const int dy1c = dy1 < 0 ? 0 : (dy1 > 4 ? 4 : dy1);
                    const float* cb = w2raw + lane * 300 + ci * 25;
                    const float* r0 = cb + dy0c * 5;
                    const float* r1 = cb + dy1c * 5;
#pragma unroll
                    for (int j = 0; j < 8; ++j) {
                        const int dx = px - j;
                        const int dxc = dx < 0 ? 0 : (dx > 4 ? 4 : dx);
                        v2r2[j].x = fmaf(r0[dxc], ((m0 >> j) & 1u) ? 1.0f : 0.0f, v2r2[j].x);
                        v2r2[j].y = fmaf(r1[dxc], ((m1 >> j) & 1u) ? 1.0f : 0.0f, v2r2[j].y);
                    }
                }
            }
        }
        // layer2: stepwise bias pk-add + max-screen + rare exact pass
        {
            PKADD(v2r2[0], b2p); PKADD(v2r2[1], b2p);
            PKADD(v2r2[2], b2p); PKADD(v2r2[3], b2p);
            PKADD(v2r2[4], b2p); PKADD(v2r2[5], b2p);
            PKADD(v2r2[6], b2p); PKADD(v2r2[7], b2p);
            float m2 = fmaxf(fmaxf(fmaxf(v2r2[0].x, v2r2[0].y), fmaxf(v2r2[1].x, v2r2[1].y)),
                             fmaxf(fmaxf(v2r2[2].x, v2r2[2].y), fmaxf(v2r2[3].x, v2r2[3].y)));
            m2 = fmaxf(m2, fmaxf(fmaxf(fmaxf(v2r2[4].x, v2r2[4].y), fmaxf(v2r2[5].x, v2r2[5].y)),
                                 fmaxf(fmaxf(v2r2[6].x, v2r2[6].y), fmaxf(v2r2[7].x, v2r2[7].y))));
            if (m2 >= th) {
#pragma unroll
                for (int j = 0; j < 8; ++j) {
#pragma unroll
                    for (int el = 0; el < 2; ++el) {
                        const float v = el ? v2r2[j].y : v2r2[j].x;
                        if (v >= th) {
                            if (el) v2r2[j].y = -__builtin_inff();
                            else    v2r2[j].x = -__builtin_inff();
                            const int oy = oyb_s + el;
                            const int p2 = ((oy >> 1) * 4 + (j >> 1)) * 64 + lane;  // NHWC flat
                            const unsigned bit = 1u << (p2 & 31);
                            const unsigned old = atomicOr(&pm2[p2 >> 5], bit);
                            if (!(old & bit)) {
                                const int pos = atomicAdd(&e2_cnt, 1);
                                e2list[pos] = ((unsigned)t << 16) | (unsigned)p2;
                            }
                        }
                    }
                }
            }
        }
        // no second barrier: next step's phase 1 touches only ev1b[(t+1)&1]/cnt1[t+1]
    }
    __syncthreads();                           // e2list complete

    // ---- output layer: replay t-sorted layer2 event log (no feedback) ----
    if (tid < 10) {
        const int n2 = e2_cnt;
        const float b3v = b3g[tid];
        float v = 0.0f;
        float ot = NOT_FIREDf;
        int ptr = 0;
        for (int t = 0; t < 80; ++t) {
            float acc = 0.0f;
            while (ptr < n2 && (int)(e2list[ptr] >> 16) == t) {
                acc += fcw[(e2list[ptr] & 0xFFFFu) * 10 + tid];
                ++ptr;
            }
            v += acc + b3v;
            if (ot == NOT_FIREDf && v >= th_lds[t]) ot = (float)t;
        }
        out[bimg * 10 + tid] = ot;
    }
}

extern "C" void kernel_launch(void* const* d_in, const int* in_sizes, int n_in,
                              void* d_out, int out_size, void* d_ws, size_t ws_size,
                              hipStream_t stream) {
    const float* img = (const float*)d_in[0];
    const float* w1  = (const float*)d_in[1];
    const float* b1  = (const float*)d_in[2];
    const float* w2  = (const float*)d_in[3];
    const float* b2  = (const float*)d_in[4];
    const float* fcw = (const float*)d_in[5];
    const float* b3  = (const float*)d_in[6];
    float* out = (float*)d_out;

    const int B = in_sizes[0] / (28 * 28);

    float* w2p = (float*)d_ws;
    const int use_t = (ws_size >= 74176u * sizeof(float)) ? 1 : 0;
    if (use_t) {
        hipLaunchKernelGGL(w2_pad_kernel, dim3(290), dim3(256), 0, stream, w2, w2p);
        hipLaunchKernelGGL(snn_sim_kernel<1>, dim3(B), dim3(256), 0, stream,
                           img, w1, b1, b2, w2, w2p, fcw, b3, out);
    } else {
        hipLaunchKernelGGL(snn_sim_kernel<0>, dim3(B), dim3(256), 0, stream,
                           img, w1, b1, b2, w2, w2p, fcw, b3, out);
    }
}

// Round 13
// 3549.282 us; speedup vs baseline: 1.5183x; 1.0682x over previous
//
#include <hip/hip_runtime.h>
#include <math.h>

#define NOT_FIREDf 9999.0f
typedef float f32x2 __attribute__((ext_vector_type(2)));

// packed f32x2 add (bit-exact element-wise IEEE add, 1 inst for 2 adds)
#define PKADD(ACC, W) asm("v_pk_add_f32 %0, %0, %1" : "+v"(ACC) : "v"(W))

// Zero-padded conv2 weights in d_ws:
// w2p[((ci*5 + dy)*19 + rx)*64 + co] = (rx-7 in [0,5)) ? w2[(co*12+ci)*25 + dy*5 + (rx-7)] : 0
__global__ void w2_pad_kernel(const float* __restrict__ w2, float* __restrict__ w2p) {
    int idx = blockIdx.x * 256 + threadIdx.x;
    if (idx >= 72960) return;
    int co = idx & 63;
    int r = idx >> 6;            // ci*95 + dy*19 + rx
    int rx = r % 19;
    int q = r / 19;
    int dy = q % 5;
    int ci = q / 5;
    int dx = rx - 7;
    w2p[idx] = ((unsigned)dx < 5u) ? w2[(co * 12 + ci) * 25 + dy * 5 + dx] : 0.0f;
}

// v1 gather for one owned-pixel slot
#define GATHER_V1(S, Y, X) do {                                              \
    const int dy_ = py - (Y), dx_ = px - (X);                                \
    if (((unsigned)dy_ < 5u) & ((unsigned)dx_ < 5u)) {                       \
        const f32x2* wp_ = (const f32x2*)&w1s[(dy_ * 5 + dx_) * 12];         \
        PKADD(v1r[S][0], wp_[0]); PKADD(v1r[S][1], wp_[1]);                  \
        PKADD(v1r[S][2], wp_[2]); PKADD(v1r[S][3], wp_[3]);                  \
        PKADD(v1r[S][4], wp_[4]); PKADD(v1r[S][5], wp_[5]);                  \
    } } while (0)

#define P1EVENT(PK) do {                                                     \
    const int py = (int)((PK) >> 8);                                         \
    const int px = (int)((PK) & 255u);                                       \
    GATHER_V1(0, y0, x0);                                                    \
    if (has2) GATHER_V1(1, y1, x1);                                          \
  } while (0)

// stepwise bias pk-add (biases read from LDS) + max-screen + rare exact pass
#define CHECK_V1G(S, Y, X) do {                                              \
    const f32x2* bp_ = (const f32x2*)b1s;                                    \
    PKADD(v1r[S][0], bp_[0]); PKADD(v1r[S][1], bp_[1]);                      \
    PKADD(v1r[S][2], bp_[2]); PKADD(v1r[S][3], bp_[3]);                      \
    PKADD(v1r[S][4], bp_[4]); PKADD(v1r[S][5], bp_[5]);                      \
    float m_ = fmaxf(fmaxf(fmaxf(v1r[S][0].x, v1r[S][0].y),                  \
                           fmaxf(v1r[S][1].x, v1r[S][1].y)),                 \
                     fmaxf(fmaxf(v1r[S][2].x, v1r[S][2].y),                  \
                           fmaxf(v1r[S][3].x, v1r[S][3].y)));                \
    m_ = fmaxf(m_, fmaxf(fmaxf(v1r[S][4].x, v1r[S][4].y),                    \
                         fmaxf(v1r[S][5].x, v1r[S][5].y)));                  \
    if (m_ >= th) {                                                          \
        _Pragma("unroll")                                                    \
        for (int jj = 0; jj < 6; ++jj) {                                     \
            _Pragma("unroll")                                                \
            for (int el = 0; el < 2; ++el) {                                 \
                const float v_ = el ? v1r[S][jj].y : v1r[S][jj].x;           \
                if (v_ >= th) {                                              \
                    if (el) v1r[S][jj].y = -__builtin_inff();                \
                    else    v1r[S][jj].x = -__builtin_inff();                \
                    const int c_ = jj * 2 + el;                              \
                    const int pyp_ = (Y) >> 1, pxp_ = (X) >> 1;              \
                    const int p_ = c_ * 144 + pyp_ * 12 + pxp_;              \
                    const unsigned bit_ = 1u << (p_ & 31);                   \
                    const unsigned old_ = atomicOr(&pm1[p_ >> 5], bit_);     \
                    if (!(old_ & bit_)) {                                    \
                        const int pos_ = atomicAdd(&cnt1[t], 1);             \
                        ev1b[t & 1][pos_] =                                  \
                            (unsigned short)((c_ << 8) | (pyp_ << 4) | pxp_);\
                    }                                                        \
                }                                                            \
            }                                                                \
        }                                                                    \
    } } while (0)

// one phase-2 event vs this wave's single v2 row (row_s): 8 loads + 4 pk-adds
#define P2_ONE(PA) do {                                                      \
    const int dyy_ = (((PA) >> 4) & 15) - row_s;                             \
    if ((unsigned)dyy_ < 5u) {                                               \
        const int ci_ = (PA) >> 8;                                           \
        const int px_ = (PA) & 15;                                           \
        const float* q_ = w2p + ((ci_ * 5 + dyy_) * 19 + px_ + 7) * 64 + lane; \
        f32x2 la_[4];                                                        \
        _Pragma("unroll")                                                    \
        for (int i = 0; i < 4; ++i) {                                        \
            la_[i].x = q_[-((2 * i) * 64)];                                  \
            la_[i].y = q_[-((2 * i + 1) * 64)];                              \
        }                                                                    \
        _Pragma("unroll")                                                    \
        for (int i = 0; i < 4; ++i) PKADD(v2r2[i], la_[i]);                  \
    } } while (0)

template <int USE_T>
__global__ void __launch_bounds__(512, 8)
snn_sim_kernel(const float* __restrict__ img,
               const float* __restrict__ w1g,
               const float* __restrict__ b1g,
               const float* __restrict__ b2g,
               const float* __restrict__ w2raw,
               const float* __restrict__ w2p,
               const float* __restrict__ fcw,
               const float* __restrict__ b3g,
               float* __restrict__ out) {
    const int bimg = blockIdx.x;
    const int tid  = threadIdx.x;            // 0..511
    const int lane = tid & 63;
    const int wv   = tid >> 6;               // 0..7 (8 waves)
    const int row_s = __builtin_amdgcn_readfirstlane(wv);   // this wave's v2 row

    __shared__ __align__(16) float w1s[300];   // transposed: [k=ky*5+kx][c]
    __shared__ __align__(8)  float b1s[12];
    __shared__ float th_lds[80];
    __shared__ unsigned char  stin[784];
    __shared__ unsigned short evlist[784];     // t-sorted schedule, packed (py<<8|px)
    __shared__ unsigned short off[81];
    __shared__ unsigned int   hist[80];
    __shared__ __align__(8) unsigned short ev1b[2][1728];  // pooled-l1 events, dbuf
    __shared__ int            cnt1[80];        // per-step counters, never reset
    __shared__ unsigned int   pm1[54];
    __shared__ unsigned int   pm2[32];
    __shared__ unsigned int   e2list[1024];    // persistent: (t<<16) | nhwc_flat_idx
    __shared__ int            e2_cnt;

    // ---- init (stride 512) ----
    for (int i = tid; i < 300; i += 512) {
        int k = i / 12, c = i - k * 12;
        w1s[i] = w1g[c * 25 + k];
    }
    if (tid < 12) b1s[tid] = b1g[tid];
    if (tid < 80) {
        float xa = (0.0f - (float)tid) / 20.0f;
        th_lds[tid] = (float)exp((double)xa);            // correctly-rounded f32 exp
        hist[tid] = 0u;
        cnt1[tid] = 0;
    }
    if (tid < 54) pm1[tid] = 0u;
    if (tid < 32) pm2[tid] = 0u;
    if (tid == 0) e2_cnt = 0;
    for (int i = tid; i < 784; i += 512) {
        float p = img[bimg * 784 + i];
        p = fmaxf(p, 1e-5f);
        float lg = (float)log((double)p);                // correctly-rounded f32 log
        float s = ceilf(fmaxf(-17.452274f * lg, 0.0f));
        stin[i] = (unsigned char)(int)fminf(s, 255.0f);
    }
    __syncthreads();
    for (int i = tid; i < 784; i += 512) {
        int t = stin[i];
        if (t < 80) atomicAdd(&hist[t], 1u);
    }
    __syncthreads();
    if (tid == 0) {
        unsigned int acc = 0;
        for (int t = 0; t < 80; ++t) { off[t] = (unsigned short)acc; acc += hist[t]; }
        off[80] = (unsigned short)acc;
    }
    __syncthreads();
    if (tid < 80) {                            // deterministic pixel-order fill per t-bin
        int k = off[tid];
        for (int i = 0; i < 784; ++i)
            if ((int)stin[i] == tid) {
                int py = i / 28;
                evlist[k++] = (unsigned short)((py << 8) | (i - py * 28));
            }
    }
    __syncthreads();

    // ---- register state (lean) ----
    // slot 0: pixel tid (tid<576 always); slot 1 (tid<64): pixel 512+tid
    const int y0 = tid / 24,  x0 = tid - y0 * 24;
    const int has2 = (tid < 64);
    const int p1i = tid + 512;
    const int y1 = p1i / 24,  x1 = p1i - y1 * 24;
    f32x2 v1r[2][6];
#pragma unroll
    for (int s = 0; s < 2; ++s)
#pragma unroll
        for (int j = 0; j < 6; ++j) v1r[s][j] = (f32x2){0.0f, 0.0f};
    f32x2 v2r2[4];                             // cols (2i,2i+1) of row row_s, co=lane
#pragma unroll
    for (int j = 0; j < 4; ++j) v2r2[j] = (f32x2){0.0f, 0.0f};
    const float b2v = b2g[lane];
    const f32x2 b2p = (f32x2){b2v, b2v};

    // ---- time loop: ONE barrier per step ----
    for (int t = 0; t < 80; ++t) {
        const float th = th_lds[t];

        // phase 1: input events -> owned v1 pixels (unroll-4 prefetch)
        {
            const int e0 = off[t], e1t = off[t + 1];
            int e = e0;
            for (; e + 4 <= e1t; e += 4) {
                const unsigned a0 = evlist[e];
                const unsigned a1 = evlist[e + 1];
                const unsigned a2 = evlist[e + 2];
                const unsigned a3 = evlist[e + 3];
                P1EVENT(a0); P1EVENT(a1); P1EVENT(a2); P1EVENT(a3);
            }
            for (; e < e1t; ++e) { const unsigned a = evlist[e]; P1EVENT(a); }
        }
        CHECK_V1G(0, y0, x0);
        if (has2) CHECK_V1G(1, y1, x1);
        __syncthreads();                       // B1: ev1b[t&1]/cnt1[t] complete

        // phase 2: pooled-l1 events -> this wave's v2 row (4 events per ds_read_b64)
        {
            const int ne1 = cnt1[t];
            const unsigned short* evp = ev1b[t & 1];
            if (USE_T) {
                int e = 0;
                for (; e + 4 <= ne1; e += 4) {
                    const unsigned long long pk4 = *(const unsigned long long*)&evp[e];
                    const unsigned lo = (unsigned)__builtin_amdgcn_readfirstlane((int)(unsigned)pk4);
                    const unsigned hi = (unsigned)__builtin_amdgcn_readfirstlane((int)(unsigned)(pk4 >> 32));
                    const int p0 = (int)(lo & 0xFFFFu), p1 = (int)(lo >> 16);
                    const int p2 = (int)(hi & 0xFFFFu), p3 = (int)(hi >> 16);
                    P2_ONE(p0); P2_ONE(p1); P2_ONE(p2); P2_ONE(p3);
                }
                for (; e < ne1; ++e) {
                    const int p0 = __builtin_amdgcn_readfirstlane((int)evp[e]);
                    P2_ONE(p0);
                }
            } else {
                for (int e = 0; e < ne1; ++e) {
                    const int pk = __builtin_amdgcn_readfirstlane((int)evp[e]);
                    const int dy = ((pk >> 4) & 15) - row_s;
                    if ((unsigned)dy >= 5u) continue;
                    const int ci = pk >> 8;
                    const int px = pk & 15;
                    const float* r = w2raw + (lane * 12 + ci) * 25 + dy * 5;
#pragma unroll
                    for (int i = 0; i < 4; ++i) {
                        const int dxa = px - 2 * i;
                        const int dxb = dxa - 1;
                        const int dxac = dxa < 0 ? 0 : (dxa > 4 ? 4 : dxa);
                        const int dxbc = dxb < 0 ? 0 : (dxb > 4 ? 4 : dxb);
                        v2r2[i].x = fmaf(r[dxac], ((unsigned)dxa < 5u) ? 1.0f : 0.0f, v2r2[i].x);
                        v2r2[i].y = fmaf(r[dxbc], ((unsigned)dxb < 5u) ? 1.0f : 0.0f, v2r2[i].y);
                    }
                }
            }
        }
        // layer2: stepwise bias pk-add + max-screen + rare exact pass
        {
            PKADD(v2r2[0], b2p); PKADD(v2r2[1], b2p);
            PKADD(v2r2[2], b2p); PKADD(v2r2[3], b2p);
            float m2 = fmaxf(fmaxf(fmaxf(v2r2[0].x, v2r2[0].y), fmaxf(v2r2[1].x, v2r2[1].y)),
                             fmaxf(fmaxf(v2r2[2].x, v2r2[2].y), fmaxf(v2r2[3].x, v2r2[3].y)));
            if (m2 >= th) {
#pragma unroll
                for (int i = 0; i < 4; ++i) {
#pragma unroll
                    for (int el = 0; el < 2; ++el) {
                        const float v = el ? v2r2[i].y : v2r2[i].x;
                        if (v >= th) {
                            if (el) v2r2[i].y = -__builtin_inff();
                            else    v2r2[i].x = -__builtin_inff();
                            // ox = 2i+el -> pw = i; oy = row_s
                            const int p2 = ((row_s >> 1) * 4 + i) * 64 + lane;  // NHWC flat
                            const unsigned bit = 1u << (p2 & 31);
                            const unsigned old = atomicOr(&pm2[p2 >> 5], bit);
                            if (!(old & bit)) {
                                const int pos = atomicAdd(&e2_cnt, 1);
                                e2list[pos] = ((unsigned)t << 16) | (unsigned)p2;
                            }
                        }
                    }
                }
            }
        }
        // no second barrier: next step's phase 1 touches only ev1b[(t+1)&1]/cnt1[t+1]
    }
    __syncthreads();                           // e2list complete

    // ---- output layer: replay t-sorted layer2 event log (no feedback) ----
    if (tid < 10) {
        const int n2 = e2_cnt;
        const float b3v = b3g[tid];
        float v = 0.0f;
        float ot = NOT_FIREDf;
        int ptr = 0;
        for (int t = 0; t < 80; ++t) {
            float acc = 0.0f;
            while (ptr < n2 && (int)(e2list[ptr] >> 16) == t) {
                acc += fcw[(e2list[ptr] & 0xFFFFu) * 10 + tid];
                ++ptr;
            }
            v += acc + b3v;
            if (ot == NOT_FIREDf && v >= th_lds[t]) ot = (float)t;
        }
        out[bimg * 10 + tid] = ot;
    }
}

extern "C" void kernel_launch(void* const* d_in, const int* in_sizes, int n_in,
                              void* d_out, int out_size, void* d_ws, size_t ws_size,
                              hipStream_t stream) {
    const float* img = (const float*)d_in[0];
    const float* w1  = (const float*)d_in[1];
    const float* b1  = (const float*)d_in[2];
    const float* w2  = (const float*)d_in[3];
    const float* b2  = (const float*)d_in[4];
    const float* fcw = (const float*)d_in[5];
    const float* b3  = (const float*)d_in[6];
    float* out = (float*)d_out;

    const int B = in_sizes[0] / (28 * 28);

    float* w2p = (float*)d_ws;
    const int use_t = (ws_size >= 72960u * sizeof(float)) ? 1 : 0;
    if (use_t) {
        hipLaunchKernelGGL(w2_pad_kernel, dim3(285), dim3(256), 0, stream, w2, w2p);
        hipLaunchKernelGGL(snn_sim_kernel<1>, dim3(B), dim3(512), 0, stream,
                           img, w1, b1, b2, w2, w2p, fcw, b3, out);
    } else {
        hipLaunchKernelGGL(snn_sim_kernel<0>, dim3(B), dim3(512), 0, stream,
                           img, w1, b1, b2, w2, w2p, fcw, b3, out);
    }
}

// Round 14
// 3246.836 us; speedup vs baseline: 1.6598x; 1.0932x over previous
//
#include <hip/hip_runtime.h>
#include <math.h>

#define NOT_FIREDf 9999.0f
typedef float f32x2 __attribute__((ext_vector_type(2)));

// packed f32x2 add (bit-exact element-wise IEEE add, 1 inst for 2 adds)
#define PKADD(ACC, W) asm("v_pk_add_f32 %0, %0, %1" : "+v"(ACC) : "v"(W))

// Zero-padded conv2 weights in d_ws:
// w2p[((ci*5 + dy)*19 + rx)*64 + co] = (rx-7 in [0,5)) ? w2[(co*12+ci)*25 + dy*5 + (rx-7)] : 0
// plus a 19*64 zero row at w2p + 72960.
__global__ void w2_pad_kernel(const float* __restrict__ w2, float* __restrict__ w2p) {
    int idx = blockIdx.x * 256 + threadIdx.x;
    if (idx >= 74176) return;
    if (idx >= 72960) { w2p[idx] = 0.0f; return; }
    int co = idx & 63;
    int r = idx >> 6;            // ci*95 + dy*19 + rx
    int rx = r % 19;
    int q = r / 19;
    int dy = q % 5;
    int ci = q / 5;
    int dx = rx - 7;
    w2p[idx] = ((unsigned)dx < 5u) ? w2[(co * 12 + ci) * 25 + dy * 5 + dx] : 0.0f;
}

// v1 gather: 6 pk-adds of one w1 row (12 ch) into reg pairs
#define GATHER_V1(S, Y, X) do {                                              \
    const int dy_ = py - (Y), dx_ = px - (X);                                \
    if (((unsigned)dy_ < 5u) & ((unsigned)dx_ < 5u)) {                       \
        const f32x2* wp_ = (const f32x2*)&w1s[(dy_ * 5 + dx_) * 12];         \
        PKADD(v1r[S][0], wp_[0]); PKADD(v1r[S][1], wp_[1]);                  \
        PKADD(v1r[S][2], wp_[2]); PKADD(v1r[S][3], wp_[3]);                  \
        PKADD(v1r[S][4], wp_[4]); PKADD(v1r[S][5], wp_[5]);                  \
    } } while (0)

#define P1EVENT(PK) do {                                                     \
    const int py = (int)((PK) >> 8);                                         \
    const int px = (int)((PK) & 255u);                                       \
    GATHER_V1(0, y0, x0);                                                    \
    GATHER_V1(1, y1, x1);                                                    \
    if (has2) GATHER_V1(2, y2, x2);                                          \
  } while (0)

// stepwise bias pk-add (biases read from LDS, no persistent regs) + max-screen
#define CHECK_V1G(S, Y, X) do {                                              \
    const f32x2* bp_ = (const f32x2*)b1s;                                    \
    PKADD(v1r[S][0], bp_[0]); PKADD(v1r[S][1], bp_[1]);                      \
    PKADD(v1r[S][2], bp_[2]); PKADD(v1r[S][3], bp_[3]);                      \
    PKADD(v1r[S][4], bp_[4]); PKADD(v1r[S][5], bp_[5]);                      \
    float m_ = fmaxf(fmaxf(fmaxf(v1r[S][0].x, v1r[S][0].y),                  \
                           fmaxf(v1r[S][1].x, v1r[S][1].y)),                 \
                     fmaxf(fmaxf(v1r[S][2].x, v1r[S][2].y),                  \
                           fmaxf(v1r[S][3].x, v1r[S][3].y)));                \
    m_ = fmaxf(m_, fmaxf(fmaxf(v1r[S][4].x, v1r[S][4].y),                    \
                         fmaxf(v1r[S][5].x, v1r[S][5].y)));                  \
    if (m_ >= th) {                                                          \
        _Pragma("unroll")                                                    \
        for (int jj = 0; jj < 6; ++jj) {                                     \
            _Pragma("unroll")                                                \
            for (int el = 0; el < 2; ++el) {                                 \
                const float v_ = el ? v1r[S][jj].y : v1r[S][jj].x;           \
                if (v_ >= th) {                                              \
                    if (el) v1r[S][jj].y = -__builtin_inff();                \
                    else    v1r[S][jj].x = -__builtin_inff();                \
                    const int c_ = jj * 2 + el;                              \
                    const int pyp_ = (Y) >> 1, pxp_ = (X) >> 1;              \
                    const int p_ = c_ * 144 + pyp_ * 12 + pxp_;              \
                    const unsigned bit_ = 1u << (p_ & 31);                   \
                    const unsigned old_ = atomicOr(&pm1[p_ >> 5], bit_);     \
                    if (!(old_ & bit_)) {                                    \
                        const int pos_ = atomicAdd(&cnt1[t], 1);             \
                        ev1b[t & 1][pos_] =                                  \
                            (unsigned short)((c_ << 8) | (pyp_ << 4) | pxp_);\
                    }                                                        \
                }                                                            \
            }                                                                \
        }                                                                    \
    } } while (0)

// one phase-2 event: two la_[4] half-batches (8 live temps instead of 16);
// per-accumulator FP order unchanged (one weight add per event)
#define P2_ONE(PA) do {                                                      \
    const int dA_ = (((PA) >> 4) & 15) - oyb_s;                              \
    if ((unsigned)dA_ < 6u) {                                                \
        const int ci_ = (PA) >> 8;                                           \
        const int px_ = (PA) & 15;                                           \
        const float* r0_ = (dA_ <= 4) ? (w2p + (ci_ * 5 + dA_) * 1216) : zrow; \
        const float* r1_ = (dA_ >= 1) ? (w2p + (ci_ * 5 + dA_ - 1) * 1216) : zrow; \
        const float* q0_ = r0_ + (px_ + 7) * 64 + lane;                      \
        const float* q1_ = r1_ + (px_ + 7) * 64 + lane;                      \
        f32x2 la_[4];                                                        \
        _Pragma("unroll")                                                    \
        for (int j = 0; j < 4; ++j) { la_[j].x = q0_[-(j * 64)]; la_[j].y = q1_[-(j * 64)]; } \
        _Pragma("unroll")                                                    \
        for (int j = 0; j < 4; ++j) PKADD(v2r2[j], la_[j]);                  \
        _Pragma("unroll")                                                    \
        for (int j = 0; j < 4; ++j) { la_[j].x = q0_[-((4 + j) * 64)]; la_[j].y = q1_[-((4 + j) * 64)]; } \
        _Pragma("unroll")                                                    \
        for (int j = 0; j < 4; ++j) PKADD(v2r2[4 + j], la_[j]);              \
    } } while (0)

template <int USE_T>
__global__ void __launch_bounds__(256, 4)
snn_sim_kernel(const float* __restrict__ img,
               const float* __restrict__ w1g,
               const float* __restrict__ b1g,
               const float* __restrict__ b2g,
               const float* __restrict__ w2raw,
               const float* __restrict__ w2p,
               const float* __restrict__ fcw,
               const float* __restrict__ b3g,
               float* __restrict__ out) {
    const int bimg = blockIdx.x;
    const int tid  = threadIdx.x;
    const int lane = tid & 63;
    const int wv   = tid >> 6;   // 4 waves
    const int oyb_s = __builtin_amdgcn_readfirstlane(wv) * 2;   // wave-uniform SGPR

    __shared__ __align__(16) float w1s[300];   // transposed: [k=ky*5+kx][c]
    __shared__ __align__(8)  float b1s[12];
    __shared__ float th_lds[80];
    __shared__ unsigned char  stin[784];
    __shared__ unsigned short evlist[784];     // t-sorted schedule, packed (py<<8|px)
    __shared__ unsigned short off[81];
    __shared__ unsigned int   hist[80];
    __shared__ __align__(8) unsigned short ev1b[2][1728];  // pooled-l1 events, dbuf
    __shared__ int            cnt1[80];        // per-step counters, never reset
    __shared__ unsigned int   pm1[54];
    __shared__ unsigned int   pm2[32];
    __shared__ unsigned int   e2list[1024];    // persistent: (t<<16) | nhwc_flat_idx
    __shared__ int            e2_cnt;

    // ---- init ----
    for (int i = tid; i < 300; i += 256) {
        int k = i / 12, c = i - k * 12;
        w1s[i] = w1g[c * 25 + k];
    }
    if (tid < 12) b1s[tid] = b1g[tid];
    if (tid < 80) {
        float xa = (0.0f - (float)tid) / 20.0f;
        th_lds[tid] = (float)exp((double)xa);            // correctly-rounded f32 exp
        hist[tid] = 0u;
        cnt1[tid] = 0;
    }
    if (tid < 54) pm1[tid] = 0u;
    if (tid < 32) pm2[tid] = 0u;
    if (tid == 0) e2_cnt = 0;
    for (int i = tid; i < 784; i += 256) {
        float p = img[bimg * 784 + i];
        p = fmaxf(p, 1e-5f);
        float lg = (float)log((double)p);                // correctly-rounded f32 log
        float s = ceilf(fmaxf(-17.452274f * lg, 0.0f));
        stin[i] = (unsigned char)(int)fminf(s, 255.0f);
    }
    __syncthreads();
    for (int i = tid; i < 784; i += 256) {
        int t = stin[i];
        if (t < 80) atomicAdd(&hist[t], 1u);
    }
    __syncthreads();
    if (tid == 0) {
        unsigned int acc = 0;
        for (int t = 0; t < 80; ++t) { off[t] = (unsigned short)acc; acc += hist[t]; }
        off[80] = (unsigned short)acc;
    }
    __syncthreads();
    if (tid < 80) {                            // deterministic pixel-order fill per t-bin
        int k = off[tid];
        for (int i = 0; i < 784; ++i)
            if ((int)stin[i] == tid) {
                int py = i / 28;
                evlist[k++] = (unsigned short)((py << 8) | (i - py * 28));
            }
    }
    __syncthreads();

    // ---- register state ----
    f32x2 v1r[3][6];
#pragma unroll
    for (int s = 0; s < 3; ++s)
#pragma unroll
        for (int j = 0; j < 6; ++j) v1r[s][j] = (f32x2){0.0f, 0.0f};
    f32x2 v2r2[8];                             // .x = row oyb, .y = row oyb+1, col j, co=lane
#pragma unroll
    for (int j = 0; j < 8; ++j) v2r2[j] = (f32x2){0.0f, 0.0f};

    const float b2v = b2g[lane];
    const f32x2 b2p = (f32x2){b2v, b2v};
    const float* zrow = w2p + 72960;

    const int y0 = tid / 24,  x0 = tid - y0 * 24;
    const int p1i = tid + 256;
    const int y1 = p1i / 24,  x1 = p1i - y1 * 24;
    const int has2 = (tid < 64);
    const int p2i = tid + 512;
    const int y2 = p2i / 24,  x2 = p2i - y2 * 24;

    // ---- time loop: ONE barrier per step ----
    for (int t = 0; t < 80; ++t) {
        const float th = th_lds[t];

        // phase 1: gather input events into v1 reg pairs (unroll-4 prefetch)
        {
            const int e0 = off[t], e1t = off[t + 1];
            int e = e0;
            for (; e + 4 <= e1t; e += 4) {
                const unsigned a0 = evlist[e];
                const unsigned a1 = evlist[e + 1];
                const unsigned a2 = evlist[e + 2];
                const unsigned a3 = evlist[e + 3];
                P1EVENT(a0); P1EVENT(a1); P1EVENT(a2); P1EVENT(a3);
            }
            for (; e < e1t; ++e) { const unsigned a = evlist[e]; P1EVENT(a); }
        }
        CHECK_V1G(0, y0, x0);
        CHECK_V1G(1, y1, x1);
        if (has2) CHECK_V1G(2, y2, x2);
        __syncthreads();                       // B1: ev1b[t&1]/cnt1[t] complete

        // phase 2: pooled-l1 events -> v2 (4 events per ds_read_b64)
        {
            const int ne1 = cnt1[t];
            const unsigned short* evp = ev1b[t & 1];
            if (USE_T) {
                int e = 0;
                for (; e + 4 <= ne1; e += 4) {
                    const unsigned long long pk4 = *(const unsigned long long*)&evp[e];
                    const unsigned lo = (unsigned)__builtin_amdgcn_readfirstlane((int)(unsigned)pk4);
                    const unsigned hi = (unsigned)__builtin_amdgcn_readfirstlane((int)(unsigned)(pk4 >> 32));
                    const int p0 = (int)(lo & 0xFFFFu), p1 = (int)(lo >> 16);
                    const int p2 = (int)(hi & 0xFFFFu), p3 = (int)(hi >> 16);
                    P2_ONE(p0); P2_ONE(p1); P2_ONE(p2); P2_ONE(p3);
                }
                for (; e < ne1; ++e) {
                    const int p0 = __builtin_amdgcn_readfirstlane((int)evp[e]);
                    P2_ONE(p0);
                }
            } else {
                for (int e = 0; e < ne1; ++e) {
                    const int pk = __builtin_amdgcn_readfirstlane((int)evp[e]);
                    const int dy0 = ((pk >> 4) & 15) - oyb_s;
                    if ((unsigned)dy0 >= 6u) continue;
                    const int ci = pk >> 8;
                    const int px = pk & 15;
                    const int dy1 = dy0 - 1;
                    const unsigned colm = ((0x1Fu << px) >> 4) & 0xFFu;
                    const unsigned m0 = ((unsigned)dy0 < 5u) ? colm : 0u;
                    const unsigned m1 = ((unsigned)dy1 < 5u) ? colm : 0u;
                    const int dy0c = dy0 < 0 ? 0 : (dy0 > 4 ? 4 : dy0);
                    const int dy1c = dy1 < 0 ? 0 : (dy1 > 4 ? 4 : dy1);
                    const float* cb = w2raw + lane * 300 + ci * 25;
                    const float* r0 = cb + dy0c * 5;
                    const float* r1 = cb + dy1c * 5;
#pragma unroll
                    for (int j = 0; j < 8; ++j) {
                        const int dx = px - j;
                        const int dxc = dx < 0 ? 0 : (dx > 4 ? 4 : dx);
                        v2r2[j].x = fmaf(r0[dxc], ((m0 >> j) & 1u) ? 1.0f : 0.0f, v2r2[j].x);
                        v2r2[j].y = fmaf(r1[dxc], ((m1 >> j) & 1u) ? 1.0f : 0.0f, v2r2[j].y);
                    }
                }
            }
        }
        // layer2: stepwise bias pk-add + max-screen + rare exact pass
        {
            PKADD(v2r2[0], b2p); PKADD(v2r2[1], b2p);
            PKADD(v2r2[2], b2p); PKADD(v2r2[3], b2p);
            PKADD(v2r2[4], b2p); PKADD(v2r2[5], b2p);
            PKADD(v2r2[6], b2p); PKADD(v2r2[7], b2p);
            float m2 = fmaxf(fmaxf(fmaxf(v2r2[0].x, v2r2[0].y), fmaxf(v2r2[1].x, v2r2[1].y)),
                             fmaxf(fmaxf(v2r2[2].x, v2r2[2].y), fmaxf(v2r2[3].x, v2r2[3].y)));
            m2 = fmaxf(m2, fmaxf(fmaxf(fmaxf(v2r2[4].x, v2r2[4].y), fmaxf(v2r2[5].x, v2r2[5].y)),
                                 fmaxf(fmaxf(v2r2[6].x, v2r2[6].y), fmaxf(v2r2[7].x, v2r2[7].y))));
            if (m2 >= th) {
#pragma unroll
                for (int j = 0; j < 8; ++j) {
#pragma unroll
                    for (int el = 0; el < 2; ++el) {
                        const float v = el ? v2r2[j].y : v2r2[j].x;
                        if (v >= th) {
                            if (el) v2r2[j].y = -__builtin_inff();
                            else    v2r2[j].x = -__builtin_inff();
                            const int oy = oyb_s + el;
                            const int p2 = ((oy >> 1) * 4 + (j >> 1)) * 64 + lane;  // NHWC flat
                            const unsigned bit = 1u << (p2 & 31);
                            const unsigned old = atomicOr(&pm2[p2 >> 5], bit);
                            if (!(old & bit)) {
                                const int pos = atomicAdd(&e2_cnt, 1);
                                e2list[pos] = ((unsigned)t << 16) | (unsigned)p2;
                            }
                        }
                    }
                }
            }
        }
        // no second barrier: next step's phase 1 touches only ev1b[(t+1)&1]/cnt1[t+1]
    }
    __syncthreads();                           // e2list complete

    // ---- output layer: replay t-sorted layer2 event log (no feedback) ----
    if (tid < 10) {
        const int n2 = e2_cnt;
        const float b3v = b3g[tid];
        float v = 0.0f;
        float ot = NOT_FIREDf;
        int ptr = 0;
        for (int t = 0; t < 80; ++t) {
            float acc = 0.0f;
            while (ptr < n2 && (int)(e2list[ptr] >> 16) == t) {
                acc += fcw[(e2list[ptr] & 0xFFFFu) * 10 + tid];
                ++ptr;
            }
            v += acc + b3v;
            if (ot == NOT_FIREDf && v >= th_lds[t]) ot = (float)t;
        }
        out[bimg * 10 + tid] = ot;
    }
}

extern "C" void kernel_launch(void* const* d_in, const int* in_sizes, int n_in,
                              void* d_out, int out_size, void* d_ws, size_t ws_size,
                              hipStream_t stream) {
    const float* img = (const float*)d_in[0];
    const float* w1  = (const float*)d_in[1];
    const float* b1  = (const float*)d_in[2];
    const float* w2  = (const float*)d_in[3];
    const float* b2  = (const float*)d_in[4];
    const float* fcw = (const float*)d_in[5];
    const float* b3  = (const float*)d_in[6];
    float* out = (float*)d_out;

    const int B = in_sizes[0] / (28 * 28);

    float* w2p = (float*)d_ws;
    const int use_t = (ws_size >= 74176u * sizeof(float)) ? 1 : 0;
    if (use_t) {
        hipLaunchKernelGGL(w2_pad_kernel, dim3(290), dim3(256), 0, stream, w2, w2p);
        hipLaunchKernelGGL(snn_sim_kernel<1>, dim3(B), dim3(256), 0, stream,
                           img, w1, b1, b2, w2, w2p, fcw, b3, out);
    } else {
        hipLaunchKernelGGL(snn_sim_kernel<0>, dim3(B), dim3(256), 0, stream,
                           img, w1, b1, b2, w2, w2p, fcw, b3, out);
    }
}